// Round 9
// baseline (1095.263 us; speedup 1.0000x reference)
//
#include <hip/hip_runtime.h>
#include <hip/hip_cooperative_groups.h>
#include <stdint.h>

namespace cg = cooperative_groups;

#define N_NODES 50000
#define N_EDGES 500000
#define NPAD    50048   // 391 * 128
#define NBLK    128     // edge chunks per set
#define EPB     4096    // edges per chunk (256 threads * 16)
#define NBUCK   391     // ceil(50000/128) buckets of 128 nodes
#define LFLAT   50048   // NBUCK*128 flattened (bucket,chunk) per set
#define NSC2    196     // scan chunks per set = ceil(50048/256)
#define P4CAP   4096    // max edges per bucket staged in LDS (actual max ~1500)
#define NB      1024    // cooperative grid size (4 blocks/CU <= 6 LDS-limited)
#define EPS     1e-5f

typedef _Float16 half8_ __attribute__((ext_vector_type(8)));
typedef _Float16 half4_ __attribute__((ext_vector_type(4)));
typedef float    float4_ __attribute__((ext_vector_type(4)));

typedef uint32_t u32_g __attribute__((address_space(1)));
typedef uint32_t u32_s __attribute__((address_space(3)));

__device__ __forceinline__ void gload16(const void* g, void* lds_wave_base) {
    __builtin_amdgcn_global_load_lds((const u32_g*)g, (u32_s*)lds_wave_base, 16, 0, 0);
}

// ================= build_all: prep + CSR build in ONE cooperative dispatch ========
// A: p1 hist+rank | copyx | wcat | pad | bias      (grid-stride, 14459 vblocks)
// B: per-chunk local scan (392 blocks, no atomics) | B2: scan chunk totals (2 blocks)
// C: p3 scatter | D: p4 per-bucket CSR build
__global__ __launch_bounds__(256) void build_all(
        const int* __restrict__ e1, const int* __restrict__ e2,
        int* __restrict__ G, unsigned short* __restrict__ rank16,
        const float* __restrict__ x, _Float16* __restrict__ xh,
        _Float16* __restrict__ aggb, _Float16* __restrict__ h1,
        const float* __restrict__ Wl, const float* __restrict__ W0,
        const float* __restrict__ W1, const float* __restrict__ Wout,
        _Float16* __restrict__ Wcat,
        const float* __restrict__ bl, const float* __restrict__ b0,
        const float* __restrict__ b1, const float* __restrict__ bout,
        float* __restrict__ bias,
        int* __restrict__ ctot,          // [2*NSC2] chunk totals -> exclusive offsets
        int* __restrict__ start2, unsigned int* __restrict__ tmp,
        int* __restrict__ rp, int* __restrict__ col) {
    __shared__ __align__(16) char uls[25856];   // union LDS: max over phases (p4 25600)
    cg::grid_group grid = cg::this_grid();
    const int bid = blockIdx.x;
    const int tid = threadIdx.x;

    // ---------------- phase A ----------------
    for (int vb = bid; vb < 14459; vb += NB) {
        if (vb < 256) {
            // p1: per-chunk bucket histogram + local rank (LDS atomics only)
            int* hist = (int*)uls;
            const int s = vb >> 7, blk = vb & 127;
            const int* dst = s ? e2 : e1;
            unsigned short* rk = rank16 + (size_t)s * N_EDGES;
            for (int b = tid; b < NBUCK; b += 256) hist[b] = 0;
            __syncthreads();
            const int e0 = blk * EPB;
            int myrank[16];
#pragma unroll
            for (int k = 0; k < 16; k++) {
                int i = e0 + k * 256 + tid;
                int r = 0;
                if (i < N_EDGES) r = atomicAdd(&hist[dst[i] >> 7], 1);   // ds_add_rtn
                myrank[k] = r;
            }
#pragma unroll
            for (int k = 0; k < 16; k++) {
                int i = e0 + k * 256 + tid;
                if (i < N_EDGES) rk[i] = (unsigned short)myrank[k];
            }
            __syncthreads();
            int* Gp = G + (s * NBLK + blk) * NBUCK;
            for (int b = tid; b < NBUCK; b += 256) Gp[b] = hist[b];
            __syncthreads();
        } else if (vb < 12756) {
            // copyx: fp32 -> fp16
            int i = (vb - 256) * 256 + tid;            // < 3,200,000 exact
            float4_ v = ((const float4_*)x)[i];
            half4_ h;
            h[0] = (_Float16)v[0]; h[1] = (_Float16)v[1];
            h[2] = (_Float16)v[2]; h[3] = (_Float16)v[3];
            ((half4_*)xh)[i] = h;
        } else if (vb < 14420) {
            // wcat: [Wl|W0|W1] rows fp16, then Wout fp16
            int i = (vb - 12756) * 256 + tid;          // < 425984 exact
            if (i < 2 * 256 * 768) {
                int l = i / (256 * 768);
                int r = i % (256 * 768);
                int j = r / 768, k = r % 768;
                const float* s = (k < 256) ? Wl : (k < 512 ? W0 : W1);
                Wcat[i] = (_Float16)s[l * 65536 + j * 256 + (k & 255)];
            } else {
                Wcat[i] = (_Float16)Wout[i - 2 * 256 * 768];
            }
        } else if (vb < 14456) {
            // pad rows [N,NPAD) of xh, aggb, h1
            int j = (vb - 14420) * 256 + tid;          // < 9216
            int buf = j / 3072, jj = j % 3072;
            _Float16* p = (buf == 0) ? xh : (buf == 1) ? aggb : h1;
            half4_ z = {(_Float16)0.f, (_Float16)0.f, (_Float16)0.f, (_Float16)0.f};
            *(half4_*)(p + (size_t)N_NODES * 256 + (size_t)jj * 4) = z;
        } else {
            int i = (vb - 14456) * 256 + tid;
            if (i < 512)      bias[i] = bl[i] + b0[i] + b1[i];
            else if (i < 640) bias[i] = bout[i - 512];
        }
    }
    __threadfence();
    grid.sync();

    // ---------------- phase B: per-chunk local exclusive scan (no atomics) --------
    if (bid < 2 * NSC2) {
        int* sm = (int*)uls;
        const int s = bid / NSC2;
        const int seq = bid % NSC2;
        const int t = tid;
        const int i = seq * 256 + t;
        int v = 0;
        if (i < LFLAT) v = G[(s * NBLK + (i & 127)) * NBUCK + (i >> 7)];
        sm[t] = v;
        __syncthreads();
        for (int off = 1; off < 256; off <<= 1) {
            int xv = sm[t];
            if (t >= off) xv += sm[t - off];
            __syncthreads();
            sm[t] = xv;
            __syncthreads();
        }
        if (i < LFLAT) start2[s * LFLAT + i] = sm[t] - v;   // chunk-local exclusive
        if (t == 255) ctot[bid] = sm[255];                  // chunk total
    }
    __threadfence();
    grid.sync();

    // ---------------- phase B2: scan chunk totals (1 block per set, in place) -----
    if (bid < 2) {
        int* sm = (int*)uls;
        const int t = tid;
        int v = (t < NSC2) ? ctot[bid * NSC2 + t] : 0;
        sm[t] = v;
        __syncthreads();
        for (int off = 1; off < 256; off <<= 1) {
            int xv = sm[t];
            if (t >= off) xv += sm[t - off];
            __syncthreads();
            sm[t] = xv;
            __syncthreads();
        }
        if (t < NSC2) ctot[bid * NSC2 + t] = sm[t] - v;     // exclusive offsets
    }
    __threadfence();
    grid.sync();

    // ---------------- phase C: p3 scatter into bucket-grouped tmp ----------------
    if (bid < 256) {
        const int s = bid >> 7, blk = bid & 127;
        const int* ed = s ? e2 : e1;
        const int* st = start2 + s * LFLAT;
        const int* cofs = ctot + s * NSC2;
        const unsigned short* rk = rank16 + (size_t)s * N_EDGES;
        unsigned int* tp = tmp + (size_t)s * N_EDGES;
        const int e0 = blk * EPB;
#pragma unroll
        for (int k = 0; k < 16; k++) {
            int i = e0 + k * 256 + tid;
            if (i < N_EDGES) {
                int d   = ed[i];
                int src = ed[N_EDGES + i];
                int f   = (d >> 7) * NBLK + blk;
                int pos = st[f] + cofs[f >> 8] + (int)rk[i];
                tp[pos] = ((unsigned)(d & 127) << 16) | (unsigned)src;
            }
        }
    }
    __threadfence();
    grid.sync();

    // ---------------- phase D: p4 per-bucket CSR build ----------------
    for (int vb = bid; vb < 2 * NBUCK; vb += NB) {
        int* cnt = (int*)uls;
        int* off = (int*)(uls + 512);
        unsigned int*   stM = (unsigned int*)(uls + 1024);
        unsigned short* stS = (unsigned short*)(uls + 1024 + 16384);
        const int s = vb / NBUCK;
        const int b = vb - s * NBUCK;
        const int t = tid;
        const int* st = start2 + s * LFLAT;
        const int* cofs = ctot + s * NSC2;
        const int A   = st[b * NBLK] + cofs[(b * NBLK) >> 8];
        const int Bnd = (b == NBUCK - 1) ? N_EDGES
                        : st[(b + 1) * NBLK] + cofs[((b + 1) * NBLK) >> 8];
        const unsigned int* tp = tmp + (size_t)s * N_EDGES;

        if (t < 128) cnt[t] = 0;
        __syncthreads();
        for (int eb = A; eb < Bnd; eb += 256) {
            int e = eb + t;
            if (e < Bnd) {
                unsigned v = tp[e];
                int idx = (int)(v >> 16);
                int r = atomicAdd(&cnt[idx], 1);
                int sl = e - A;
                if (sl < P4CAP) {
                    stM[sl] = ((unsigned)idx << 12) | (unsigned)r;
                    stS[sl] = (unsigned short)(v & 0xFFFFu);
                }
            }
        }
        __syncthreads();
        if (t < 128) off[t] = cnt[t];
        __syncthreads();
        for (int d = 1; d < 128; d <<= 1) {
            int xv = 0;
            if (t < 128) { xv = off[t]; if (t >= d) xv += off[t - d]; }
            __syncthreads();
            if (t < 128) off[t] = xv;
            __syncthreads();
        }
        const int nE = Bnd - A;
        int* colS = col + (size_t)s * N_EDGES;
        for (int sl = t; sl < nE && sl < P4CAP; sl += 256) {
            unsigned m = stM[sl];
            int idx = (int)(m >> 12), r = (int)(m & 4095u);
            colS[A + off[idx] - cnt[idx] + r] = (int)stS[sl];
        }
        const int nbase = b * 128;
        if (t < 128 && nbase + t < N_NODES)
            rp[s * (N_NODES + 1) + nbase + t] = A + off[t] - cnt[t];
        if (b == NBUCK - 1 && t == 0) rp[s * (N_NODES + 1) + N_NODES] = N_EDGES;
        __syncthreads();   // LDS reuse hazard across stride iterations
    }
}

// ================= CSR pull gather: split-wave, 16B/lane, 8 rows in flight =========
__global__ void gather_kernel(const _Float16* __restrict__ hin,
                              const int* __restrict__ rowptr, const int* __restrict__ col,
                              _Float16* __restrict__ dst, int n) {
    int node = blockIdx.x * 4 + (threadIdx.x >> 6);
    int lane = threadIdx.x & 63;
    int half = lane >> 5, l5 = lane & 31;
    if (node >= n) return;
    int s = rowptr[node], e = rowptr[node + 1];
    float a[8] = {0.f, 0.f, 0.f, 0.f, 0.f, 0.f, 0.f, 0.f};
    float b[8] = {0.f, 0.f, 0.f, 0.f, 0.f, 0.f, 0.f, 0.f};
    int i = s + half;
    for (; i + 6 < e; i += 8) {
        int c0 = col[i], c1 = col[i + 2], c2 = col[i + 4], c3 = col[i + 6];
        half8_ v0 = *(const half8_*)(hin + (size_t)c0 * 256 + l5 * 8);
        half8_ v1 = *(const half8_*)(hin + (size_t)c1 * 256 + l5 * 8);
        half8_ v2 = *(const half8_*)(hin + (size_t)c2 * 256 + l5 * 8);
        half8_ v3 = *(const half8_*)(hin + (size_t)c3 * 256 + l5 * 8);
#pragma unroll
        for (int j = 0; j < 8; j++) {
            a[j] += (float)v0[j] + (float)v2[j];
            b[j] += (float)v1[j] + (float)v3[j];
        }
    }
    for (; i < e; i += 2) {
        int c0 = col[i];
        half8_ v0 = *(const half8_*)(hin + (size_t)c0 * 256 + l5 * 8);
#pragma unroll
        for (int j = 0; j < 8; j++) a[j] += (float)v0[j];
    }
    half8_ o;
#pragma unroll
    for (int j = 0; j < 8; j++) {
        float t = a[j] + b[j];
        t += __shfl_xor(t, 32, 64);
        o[j] = (_Float16)t;
    }
    if (half == 0)
        *(half8_*)(dst + (size_t)node * 256 + l5 * 8) = o;
}

// ================= fused layer GEMM: H = LN(relu([agg|h|x] @ W^T + bias)) =========
__global__ __launch_bounds__(512) void gemm_ln(const _Float16* __restrict__ agg,
                                               const _Float16* __restrict__ hsrc,
                                               const _Float16* __restrict__ xh,
                                               const _Float16* __restrict__ Bw,  // [256][768]
                                               const float* __restrict__ bias,
                                               const float* __restrict__ gamma,
                                               const float* __restrict__ beta,
                                               _Float16* __restrict__ H) {
    __shared__ __align__(16) char smem[49152];   // As 16K | Bs 32K
    char* AsB = smem;
    char* BsB = smem + 16384;
    const int rowBase = blockIdx.x * 128;
    const int tid  = threadIdx.x;
    const int lane = tid & 63;
    const int w    = tid >> 6;
    const int wm = w & 1, wn = w >> 1;
    const int quad = lane >> 4, mr = lane & 15;
    const int x7 = mr & 7;

    float4_ acc[4][4];
#pragma unroll
    for (int i = 0; i < 4; i++)
#pragma unroll
        for (int j = 0; j < 4; j++) { float4_ z4 = {0.f, 0.f, 0.f, 0.f}; acc[i][j] = z4; }

    int cA0 = w * 64 + lane, cA1 = cA0 + 512;
    int rA0 = cA0 >> 3, rA1 = cA1 >> 3;
    size_t offA0 = (size_t)(rowBase + rA0) * 256 + (((cA0 & 7) ^ (rA0 & 7)) * 8);
    size_t offA1 = (size_t)(rowBase + rA1) * 256 + (((cA1 & 7) ^ (rA1 & 7)) * 8);
    size_t offB[4];
#pragma unroll
    for (int j = 0; j < 4; j++) {
        int c = j * 512 + w * 64 + lane;
        int r = c >> 3;
        offB[j] = (size_t)r * 768 + (((c & 7) ^ (r & 7)) * 8);
    }
    void* lA0 = AsB + w * 1024;
    void* lA1 = AsB + 8192 + w * 1024;

    for (int k0 = 0; k0 < 768; k0 += 64) {
        const _Float16* src = (k0 < 256) ? agg : (k0 < 512) ? hsrc : xh;
        const int kloc = k0 & 255;
        gload16(src + offA0 + kloc, lA0);
        gload16(src + offA1 + kloc, lA1);
        gload16(Bw + offB[0] + k0, BsB + w * 1024);
        gload16(Bw + offB[1] + k0, BsB + 8192 + w * 1024);
        gload16(Bw + offB[2] + k0, BsB + 16384 + w * 1024);
        gload16(Bw + offB[3] + k0, BsB + 24576 + w * 1024);
        __syncthreads();
#pragma unroll
        for (int s = 0; s < 2; s++) {
            half8_ a[4], b[4];
#pragma unroll
            for (int im = 0; im < 4; im++) {
                int row = wm * 64 + im * 16 + mr;
                a[im] = *(const half8_*)(AsB + row * 128 + (((s * 4 + quad) ^ x7) * 16));
            }
#pragma unroll
            for (int in = 0; in < 4; in++) {
                int row = wn * 64 + in * 16 + mr;
                b[in] = *(const half8_*)(BsB + row * 128 + (((s * 4 + quad) ^ x7) * 16));
            }
#pragma unroll
            for (int im = 0; im < 4; im++)
#pragma unroll
                for (int in = 0; in < 4; in++)
                    acc[im][in] = __builtin_amdgcn_mfma_f32_16x16x32_f16(a[im], b[in], acc[im][in], 0, 0, 0);
        }
        __syncthreads();
    }

    float bv[4], gv[4], bev[4];
#pragma unroll
    for (int in = 0; in < 4; in++) {
        int colg = wn * 64 + in * 16 + mr;
        bv[in]  = bias[colg];
        gv[in]  = gamma[colg];
        bev[in] = beta[colg];
    }
    float* lnbuf   = (float*)AsB;
    float* lnstats = (float*)(AsB + 4096);

#pragma unroll
    for (int im = 0; im < 4; im++)
#pragma unroll
        for (int r = 0; r < 4; r++) {
            float s = 0.f, sq = 0.f;
#pragma unroll
            for (int in = 0; in < 4; in++) {
                float v = acc[im][in][r] + bv[in];
                v = v > 0.f ? v : 0.f;
                s += v; sq += v * v;
            }
            s  += __shfl_xor(s, 1, 64);  sq += __shfl_xor(sq, 1, 64);
            s  += __shfl_xor(s, 2, 64);  sq += __shfl_xor(sq, 2, 64);
            s  += __shfl_xor(s, 4, 64);  sq += __shfl_xor(sq, 4, 64);
            s  += __shfl_xor(s, 8, 64);  sq += __shfl_xor(sq, 8, 64);
            if (mr == 0) {
                int rl = wm * 64 + im * 16 + quad * 4 + r;
                lnbuf[(wn * 128 + rl) * 2]     = s;
                lnbuf[(wn * 128 + rl) * 2 + 1] = sq;
            }
        }
    __syncthreads();
    if (tid < 128) {
        float s  = lnbuf[tid * 2]             + lnbuf[(128 + tid) * 2]
                 + lnbuf[(256 + tid) * 2]     + lnbuf[(384 + tid) * 2];
        float sq = lnbuf[tid * 2 + 1]         + lnbuf[(128 + tid) * 2 + 1]
                 + lnbuf[(256 + tid) * 2 + 1] + lnbuf[(384 + tid) * 2 + 1];
        float mu  = s * (1.0f / 256.0f);
        float var = sq * (1.0f / 256.0f) - mu * mu;
        lnstats[tid * 2]     = mu;
        lnstats[tid * 2 + 1] = rsqrtf(var + EPS);
    }
    __syncthreads();

    _Float16* BsH = (_Float16*)BsB;
#pragma unroll
    for (int p = 0; p < 2; p++) {
        if (wm == p) {
#pragma unroll
            for (int im = 0; im < 4; im++)
#pragma unroll
                for (int r = 0; r < 4; r++) {
                    int rl = im * 16 + quad * 4 + r;
                    float mu = lnstats[(p * 64 + rl) * 2];
                    float rs = lnstats[(p * 64 + rl) * 2 + 1];
#pragma unroll
                    for (int in = 0; in < 4; in++) {
                        float v = acc[im][in][r] + bv[in];
                        v = v > 0.f ? v : 0.f;
                        BsH[rl * 256 + wn * 64 + in * 16 + mr] =
                            (_Float16)((v - mu) * rs * gv[in] + bev[in]);
                    }
                }
        }
        __syncthreads();
#pragma unroll
        for (int i = 0; i < 4; i++) {
            int c = i * 512 + tid;
            int row = c >> 5, ch = c & 31;
            half8_ v = *(const half8_*)(BsB + c * 16);
            *(half8_*)(H + (size_t)(rowBase + p * 64 + row) * 256 + ch * 8) = v;
        }
        __syncthreads();
    }
}

// ================= final GEMM: d_out = h2 @ Wout^T + bout (fp32) =================
__global__ __launch_bounds__(256) void gemm_bt(const _Float16* __restrict__ A, int lda,
                                               const _Float16* __restrict__ B, int ldb,
                                               const float* __restrict__ bias,
                                               float* __restrict__ C, int ldc,
                                               int K, int Mstore) {
    __shared__ _Float16 As[128 * 32];
    __shared__ _Float16 Bs[128 * 32];
    const int rowBase = blockIdx.x * 128;
    const int colBase = blockIdx.y * 128;
    const int tid  = threadIdx.x;
    const int lane = tid & 63;
    const int w    = tid >> 6;
    const int wm = w & 1, wn = w >> 1;
    const int quad = lane >> 4, mr = lane & 15;

    float4_ acc[4][4];
#pragma unroll
    for (int i = 0; i < 4; i++)
#pragma unroll
        for (int j = 0; j < 4; j++) { float4_ z4 = {0.f, 0.f, 0.f, 0.f}; acc[i][j] = z4; }

    const int c0  = w * 64 + lane;
    const int rA0 = c0 >> 2;
    const int ko  = (c0 & 3) * 8;
    char* AsB = (char*)As;
    char* BsB = (char*)Bs;
    void* lA0 = AsB + w * 1024;
    void* lA1 = AsB + 4096 + w * 1024;
    void* lB0 = BsB + w * 1024;
    void* lB1 = BsB + 4096 + w * 1024;
    const _Float16* gA0 = A + (size_t)(rowBase + rA0) * lda + ko;
    const _Float16* gA1 = gA0 + (size_t)64 * lda;
    const _Float16* gB0 = B + (size_t)(colBase + rA0) * ldb + ko;
    const _Float16* gB1 = gB0 + (size_t)64 * ldb;

    for (int k0 = 0; k0 < K; k0 += 32) {
        gload16(gA0 + k0, lA0);
        gload16(gA1 + k0, lA1);
        gload16(gB0 + k0, lB0);
        gload16(gB1 + k0, lB1);
        __syncthreads();
        half8_ a[4], b[4];
#pragma unroll
        for (int im = 0; im < 4; im++)
            a[im] = *(const half8_*)(AsB + ((wm * 64 + im * 16 + mr) * 64 + quad * 16));
#pragma unroll
        for (int in = 0; in < 4; in++)
            b[in] = *(const half8_*)(BsB + ((wn * 64 + in * 16 + mr) * 64 + quad * 16));
#pragma unroll
        for (int im = 0; im < 4; im++)
#pragma unroll
            for (int in = 0; in < 4; in++)
                acc[im][in] = __builtin_amdgcn_mfma_f32_16x16x32_f16(a[im], b[in], acc[im][in], 0, 0, 0);
        __syncthreads();
    }

#pragma unroll
    for (int in = 0; in < 4; in++) {
        const int colg = colBase + wn * 64 + in * 16 + mr;
        const float bv = bias[colg];
#pragma unroll
        for (int im = 0; im < 4; im++) {
            float4_ c = acc[im][in];
#pragma unroll
            for (int r = 0; r < 4; r++) {
                int row = rowBase + wm * 64 + im * 16 + quad * 4 + r;
                if (row < Mstore) C[(size_t)row * ldc + colg] = c[r] + bv;
            }
        }
    }
}

extern "C" void kernel_launch(void* const* d_in, const int* in_sizes, int n_in,
                              void* d_out, int out_size, void* d_ws, size_t ws_size,
                              hipStream_t stream) {
    const float* x    = (const float*)d_in[0];
    const int*   e1   = (const int*)d_in[1];
    const int*   e2   = (const int*)d_in[2];
    const float* Wl   = (const float*)d_in[3];
    const float* bl   = (const float*)d_in[4];
    const float* W0   = (const float*)d_in[5];
    const float* b0   = (const float*)d_in[6];
    const float* W1   = (const float*)d_in[7];
    const float* b1   = (const float*)d_in[8];
    const float* gamma= (const float*)d_in[9];
    const float* beta = (const float*)d_in[10];
    const float* Wout = (const float*)d_in[11];
    const float* bout = (const float*)d_in[12];

    char* ws = (char*)d_ws;
    size_t off = 0;
    auto alloc = [&](size_t bytes) -> char* {
        char* p = ws + off;
        off = (off + bytes + 255) & ~(size_t)255;
        return p;
    };
    _Float16* xh   = (_Float16*)alloc((size_t)NPAD * 256 * 2);
    _Float16* aggb = (_Float16*)alloc((size_t)NPAD * 256 * 2);
    _Float16* h1   = (_Float16*)alloc((size_t)NPAD * 256 * 2);
    _Float16* h2   = (_Float16*)alloc((size_t)NPAD * 256 * 2);
    _Float16* Wcat = (_Float16*)alloc((size_t)(2 * 256 * 768 + 128 * 256) * 2);
    float*    bias = (float*)alloc(640 * 4);
    int* ctot   = (int*)alloc((size_t)2 * NSC2 * 4);
    int* G      = (int*)alloc((size_t)2 * NBLK * NBUCK * 4);
    int* start2 = (int*)alloc((size_t)2 * LFLAT * 4);
    int* rp     = (int*)alloc((size_t)2 * (N_NODES + 1) * 4);
    unsigned short* rank16 = (unsigned short*)alloc((size_t)2 * N_EDGES * 2);
    unsigned int*   tmp    = (unsigned int*)alloc((size_t)2 * N_EDGES * 4);
    int* col    = (int*)alloc((size_t)2 * N_EDGES * 4);

    int* rp1 = rp, *rp2 = rp + (N_NODES + 1);
    int* col1 = col, *col2 = col + N_EDGES;

    // one cooperative dispatch: prep + scan + scatter + CSR build (no memset needed)
    void* kargs[] = {
        (void*)&e1, (void*)&e2, (void*)&G, (void*)&rank16,
        (void*)&x, (void*)&xh, (void*)&aggb, (void*)&h1,
        (void*)&Wl, (void*)&W0, (void*)&W1, (void*)&Wout, (void*)&Wcat,
        (void*)&bl, (void*)&b0, (void*)&b1, (void*)&bout, (void*)&bias,
        (void*)&ctot, (void*)&start2, (void*)&tmp, (void*)&rp, (void*)&col
    };
    hipLaunchCooperativeKernel((const void*)build_all, dim3(NB), dim3(256),
                               kargs, 0, stream);

    const int nb4 = (N_NODES + 3) / 4;
    const _Float16* WoutH = Wcat + 393216;

    // layer 1: weights idx 1, edges r2, h_in = x
    gather_kernel<<<nb4, 256, 0, stream>>>(xh, rp2, col2, aggb, N_NODES);
    gemm_ln<<<391, 512, 0, stream>>>(aggb, xh, xh, Wcat + 196608,
                                     bias + 256, gamma + 256, beta + 256, h1);
    // layer 2
    gather_kernel<<<nb4, 256, 0, stream>>>(h1, rp1, col1, aggb, N_NODES);
    gemm_ln<<<391, 512, 0, stream>>>(aggb, h1, xh, Wcat,
                                     bias, gamma, beta, h2);
    // output: d_out = h2 @ Wout^T + bout (fp32)
    gemm_bt<<<dim3(391, 1), 256, 0, stream>>>(h2, 256, WoutH, 256,
                                              bias + 512, (float*)d_out, 128, 256, N_NODES);
}

// Round 10
// 317.843 us; speedup vs baseline: 3.4459x; 3.4459x over previous
//
#include <hip/hip_runtime.h>
#include <stdint.h>

#define N_NODES 50000
#define N_EDGES 500000
#define NPAD    50048   // 391 * 128
#define NBLK    128     // edge chunks per set
#define EPB     4096    // edges per chunk (256 threads * 16)
#define NBUCK   391     // ceil(50000/128) buckets of 128 nodes
#define LFLAT   50048   // NBUCK*128 flattened (bucket,chunk) per set
#define NSC2    196     // scan blocks per set = ceil(50048/256)
#define P4CAP   4096    // max edges per bucket staged in LDS (actual max ~1500)
#define EPS     1e-5f

typedef _Float16 half8_ __attribute__((ext_vector_type(8)));
typedef _Float16 half4_ __attribute__((ext_vector_type(4)));
typedef float    float4_ __attribute__((ext_vector_type(4)));

typedef uint32_t u32_g __attribute__((address_space(1)));
typedef uint32_t u32_s __attribute__((address_space(3)));

__device__ __forceinline__ void gload16(const void* g, void* lds_wave_base) {
    __builtin_amdgcn_global_load_lds((const u32_g*)g, (u32_s*)lds_wave_base, 16, 0, 0);
}

// ================= mega prep kernel =================
// [0,256) p1 bucket count+rank | [256,12756) copyx | [12756,14420) wcat
// [14420,14456) pad | [14456,14459) bias | [14459,14460) zero lookback states
__global__ __launch_bounds__(256) void prep_kernel(
        const int* __restrict__ e1, const int* __restrict__ e2,
        int* __restrict__ G, unsigned short* __restrict__ rank16,
        const float* __restrict__ x, _Float16* __restrict__ xh,
        _Float16* __restrict__ aggb, _Float16* __restrict__ h1,
        const float* __restrict__ Wl, const float* __restrict__ W0,
        const float* __restrict__ W1, const float* __restrict__ Wout,
        _Float16* __restrict__ Wcat,
        const float* __restrict__ bl, const float* __restrict__ b0,
        const float* __restrict__ b1, const float* __restrict__ bout,
        float* __restrict__ bias,
        unsigned long long* __restrict__ states) {
    __shared__ int hist[NBUCK];
    const int bid = blockIdx.x;
    const int tid = threadIdx.x;
    if (bid < 256) {
        // ---- p1: per-chunk bucket histogram + local rank (LDS atomics only) ----
        const int s = bid >> 7, blk = bid & 127;
        const int* dst = s ? e2 : e1;
        unsigned short* rk = rank16 + (size_t)s * N_EDGES;
        for (int b = tid; b < NBUCK; b += 256) hist[b] = 0;
        __syncthreads();
        const int e0 = blk * EPB;
        int myrank[16];
#pragma unroll
        for (int k = 0; k < 16; k++) {
            int i = e0 + k * 256 + tid;
            int r = 0;
            if (i < N_EDGES) r = atomicAdd(&hist[dst[i] >> 7], 1);   // ds_add_rtn
            myrank[k] = r;
        }
#pragma unroll
        for (int k = 0; k < 16; k++) {
            int i = e0 + k * 256 + tid;
            if (i < N_EDGES) rk[i] = (unsigned short)myrank[k];
        }
        __syncthreads();
        int* Gp = G + (s * NBLK + blk) * NBUCK;
        for (int b = tid; b < NBUCK; b += 256) Gp[b] = hist[b];
    } else if (bid < 12756) {
        // ---- copyx: fp32 -> fp16 ----
        int i = (bid - 256) * 256 + tid;           // < 3,200,000 exact
        float4_ v = ((const float4_*)x)[i];
        half4_ h;
        h[0] = (_Float16)v[0]; h[1] = (_Float16)v[1];
        h[2] = (_Float16)v[2]; h[3] = (_Float16)v[3];
        ((half4_*)xh)[i] = h;
    } else if (bid < 14420) {
        // ---- wcat: [Wl|W0|W1] rows fp16, then Wout fp16 ----
        int i = (bid - 12756) * 256 + tid;         // < 425984 exact
        if (i < 2 * 256 * 768) {
            int l = i / (256 * 768);
            int r = i % (256 * 768);
            int j = r / 768, k = r % 768;
            const float* s = (k < 256) ? Wl : (k < 512 ? W0 : W1);
            Wcat[i] = (_Float16)s[l * 65536 + j * 256 + (k & 255)];
        } else {
            Wcat[i] = (_Float16)Wout[i - 2 * 256 * 768];
        }
    } else if (bid < 14456) {
        // ---- pad rows [N,NPAD) of xh, aggb, h1 ----
        int j = (bid - 14420) * 256 + tid;         // < 9216
        int buf = j / 3072, jj = j % 3072;
        _Float16* p = (buf == 0) ? xh : (buf == 1) ? aggb : h1;
        half4_ z = {(_Float16)0.f, (_Float16)0.f, (_Float16)0.f, (_Float16)0.f};
        *(half4_*)(p + (size_t)N_NODES * 256 + (size_t)jj * 4) = z;
    } else if (bid < 14459) {
        int i = (bid - 14456) * 256 + tid;
        if (i < 512)      bias[i] = bl[i] + b0[i] + b1[i];
        else if (i < 640) bias[i] = bout[i - 512];
    } else {
        // ---- zero lookback states (replaces host memset dispatch) ----
        for (int i = tid; i < 2 * NSC2; i += 256) states[i] = 0ULL;
    }
}

// ================= P2: lookback exclusive scan over bucket-major flat counts =======
// (standalone dispatch: natural dispatch order gives the lookback forward progress)
__global__ __launch_bounds__(256) void p2_scan(const int* __restrict__ G,
                                               unsigned long long* __restrict__ state,
                                               int* __restrict__ start2) {
    __shared__ int sm[256];
    __shared__ int s_excl;
    const int bid = blockIdx.x;
    const int s = bid / NSC2;
    const int seq = bid % NSC2;
    const int t = threadIdx.x;
    const int i = seq * 256 + t;
    unsigned long long* st = state + s * NSC2;

    int v = 0;
    if (i < LFLAT) v = G[(s * NBLK + (i & 127)) * NBUCK + (i >> 7)];
    sm[t] = v;
    __syncthreads();
    for (int off = 1; off < 256; off <<= 1) {
        int x = sm[t];
        if (t >= off) x += sm[t - off];
        __syncthreads();
        sm[t] = x;
        __syncthreads();
    }
    int total = sm[255];

    if (t == 0) {
        if (seq == 0) {
            atomicExch(&st[0], (2ULL << 32) | (unsigned int)total);
            s_excl = 0;
        } else {
            atomicExch(&st[seq], (1ULL << 32) | (unsigned int)total);
            int running = 0;
            int j = seq - 1;
            while (true) {
                unsigned long long sv = atomicAdd(&st[j], 0ULL);
                unsigned int tag = (unsigned int)(sv >> 32);
                if (tag == 0) continue;
                running += (int)(unsigned int)sv;
                if (tag == 2) break;
                j--;
            }
            atomicExch(&st[seq], (2ULL << 32) | (unsigned int)(running + total));
            s_excl = running;
        }
    }
    __syncthreads();
    if (i < LFLAT) start2[s * LFLAT + i] = s_excl + sm[t] - v;
}

// ================= P3: scatter edges into bucket-grouped tmp =======================
__global__ __launch_bounds__(256) void p3_scatter(const int* __restrict__ e1,
                                                  const int* __restrict__ e2,
                                                  const unsigned short* __restrict__ rank16,
                                                  const int* __restrict__ start2,
                                                  unsigned int* __restrict__ tmp) {
    const int bid = blockIdx.x;
    const int s = bid >> 7, blk = bid & 127;
    const int t = threadIdx.x;
    const int* ed = s ? e2 : e1;
    const int* st = start2 + s * LFLAT;
    const unsigned short* rk = rank16 + (size_t)s * N_EDGES;
    unsigned int* tp = tmp + (size_t)s * N_EDGES;
    const int e0 = blk * EPB;
#pragma unroll
    for (int k = 0; k < 16; k++) {
        int i = e0 + k * 256 + t;
        if (i < N_EDGES) {
            int d   = ed[i];
            int src = ed[N_EDGES + i];
            int pos = st[(d >> 7) * NBLK + blk] + (int)rk[i];
            tp[pos] = ((unsigned)(d & 127) << 16) | (unsigned)src;
        }
    }
}

// ================= P4: per-bucket CSR build (LDS count + scan), writes col + rowptr
__global__ __launch_bounds__(256) void p4_build(const unsigned int* __restrict__ tmp,
                                                const int* __restrict__ start2,
                                                int* __restrict__ rp,
                                                int* __restrict__ col) {
    __shared__ int cnt[128];
    __shared__ int off[128];
    __shared__ unsigned int   stM[P4CAP];   // idx<<12 | rank
    __shared__ unsigned short stS[P4CAP];   // src (< 65536)
    const int b = blockIdx.x;
    const int s = blockIdx.y;
    const int t = threadIdx.x;
    const int* st = start2 + s * LFLAT;
    const int A   = st[b * NBLK];
    const int Bnd = (b == NBUCK - 1) ? N_EDGES : st[(b + 1) * NBLK];
    const unsigned int* tp = tmp + (size_t)s * N_EDGES;

    if (t < 128) cnt[t] = 0;
    __syncthreads();
    for (int eb = A; eb < Bnd; eb += 256) {
        int e = eb + t;
        if (e < Bnd) {
            unsigned v = tp[e];
            int idx = (int)(v >> 16);
            int r = atomicAdd(&cnt[idx], 1);
            int sl = e - A;
            if (sl < P4CAP) {
                stM[sl] = ((unsigned)idx << 12) | (unsigned)r;
                stS[sl] = (unsigned short)(v & 0xFFFFu);
            }
        }
    }
    __syncthreads();
    if (t < 128) off[t] = cnt[t];
    __syncthreads();
    for (int d = 1; d < 128; d <<= 1) {
        int x = 0;
        if (t < 128) { x = off[t]; if (t >= d) x += off[t - d]; }
        __syncthreads();
        if (t < 128) off[t] = x;
        __syncthreads();
    }
    const int nE = Bnd - A;
    int* colS = col + (size_t)s * N_EDGES;
    for (int sl = t; sl < nE && sl < P4CAP; sl += 256) {
        unsigned m = stM[sl];
        int idx = (int)(m >> 12), r = (int)(m & 4095u);
        colS[A + off[idx] - cnt[idx] + r] = (int)stS[sl];
    }
    const int nbase = b * 128;
    if (t < 128 && nbase + t < N_NODES)
        rp[s * (N_NODES + 1) + nbase + t] = A + off[t] - cnt[t];
    if (b == NBUCK - 1 && t == 0) rp[s * (N_NODES + 1) + N_NODES] = N_EDGES;
}

// ================= CSR pull gather: split-wave, 16B/lane, 8 rows in flight =========
__global__ void gather_kernel(const _Float16* __restrict__ hin,
                              const int* __restrict__ rowptr, const int* __restrict__ col,
                              _Float16* __restrict__ dst, int n) {
    int node = blockIdx.x * 4 + (threadIdx.x >> 6);
    int lane = threadIdx.x & 63;
    int half = lane >> 5, l5 = lane & 31;
    if (node >= n) return;
    int s = rowptr[node], e = rowptr[node + 1];
    float a[8] = {0.f, 0.f, 0.f, 0.f, 0.f, 0.f, 0.f, 0.f};
    float b[8] = {0.f, 0.f, 0.f, 0.f, 0.f, 0.f, 0.f, 0.f};
    int i = s + half;
    for (; i + 6 < e; i += 8) {
        int c0 = col[i], c1 = col[i + 2], c2 = col[i + 4], c3 = col[i + 6];
        half8_ v0 = *(const half8_*)(hin + (size_t)c0 * 256 + l5 * 8);
        half8_ v1 = *(const half8_*)(hin + (size_t)c1 * 256 + l5 * 8);
        half8_ v2 = *(const half8_*)(hin + (size_t)c2 * 256 + l5 * 8);
        half8_ v3 = *(const half8_*)(hin + (size_t)c3 * 256 + l5 * 8);
#pragma unroll
        for (int j = 0; j < 8; j++) {
            a[j] += (float)v0[j] + (float)v2[j];
            b[j] += (float)v1[j] + (float)v3[j];
        }
    }
    for (; i < e; i += 2) {
        int c0 = col[i];
        half8_ v0 = *(const half8_*)(hin + (size_t)c0 * 256 + l5 * 8);
#pragma unroll
        for (int j = 0; j < 8; j++) a[j] += (float)v0[j];
    }
    half8_ o;
#pragma unroll
    for (int j = 0; j < 8; j++) {
        float t = a[j] + b[j];
        t += __shfl_xor(t, 32, 64);
        o[j] = (_Float16)t;
    }
    if (half == 0)
        *(half8_*)(dst + (size_t)node * 256 + l5 * 8) = o;
}

// ===== fused layer GEMM: H = LN(relu([agg|h|x] @ W^T + bias)).
// ===== When Wfin != null (layer 2): APPENDED phase (after acc is dead) computes
// ===== d_out tile = H_tile @ Wfin^T + bfin, re-reading the block's own L2-warm H tile.
__global__ __launch_bounds__(512) void gemm_ln(const _Float16* __restrict__ agg,
                                               const _Float16* __restrict__ hsrc,
                                               const _Float16* __restrict__ xh,
                                               const _Float16* __restrict__ Bw,  // [256][768]
                                               const float* __restrict__ bias,
                                               const float* __restrict__ gamma,
                                               const float* __restrict__ beta,
                                               _Float16* __restrict__ H,
                                               const _Float16* __restrict__ Wfin, // [128][256] or null
                                               const float* __restrict__ bfin,
                                               float* __restrict__ outp) {
    __shared__ __align__(16) char smem[49152];   // As 16K | Bs 32K
    char* AsB = smem;
    char* BsB = smem + 16384;
    const int rowBase = blockIdx.x * 128;
    const int tid  = threadIdx.x;
    const int lane = tid & 63;
    const int w    = tid >> 6;
    const int wm = w & 1, wn = w >> 1;
    const int quad = lane >> 4, mr = lane & 15;
    const int x7 = mr & 7;

    float4_ acc[4][4];
#pragma unroll
    for (int i = 0; i < 4; i++)
#pragma unroll
        for (int j = 0; j < 4; j++) { float4_ z4 = {0.f, 0.f, 0.f, 0.f}; acc[i][j] = z4; }

    int cA0 = w * 64 + lane, cA1 = cA0 + 512;
    int rA0 = cA0 >> 3, rA1 = cA1 >> 3;
    size_t offA0 = (size_t)(rowBase + rA0) * 256 + (((cA0 & 7) ^ (rA0 & 7)) * 8);
    size_t offA1 = (size_t)(rowBase + rA1) * 256 + (((cA1 & 7) ^ (rA1 & 7)) * 8);
    size_t offB[4];
#pragma unroll
    for (int j = 0; j < 4; j++) {
        int c = j * 512 + w * 64 + lane;
        int r = c >> 3;
        offB[j] = (size_t)r * 768 + (((c & 7) ^ (r & 7)) * 8);
    }
    void* lA0 = AsB + w * 1024;
    void* lA1 = AsB + 8192 + w * 1024;

    for (int k0 = 0; k0 < 768; k0 += 64) {
        const _Float16* src = (k0 < 256) ? agg : (k0 < 512) ? hsrc : xh;
        const int kloc = k0 & 255;
        gload16(src + offA0 + kloc, lA0);
        gload16(src + offA1 + kloc, lA1);
        gload16(Bw + offB[0] + k0, BsB + w * 1024);
        gload16(Bw + offB[1] + k0, BsB + 8192 + w * 1024);
        gload16(Bw + offB[2] + k0, BsB + 16384 + w * 1024);
        gload16(Bw + offB[3] + k0, BsB + 24576 + w * 1024);
        __syncthreads();
#pragma unroll
        for (int s = 0; s < 2; s++) {
            half8_ a[4], b[4];
#pragma unroll
            for (int im = 0; im < 4; im++) {
                int row = wm * 64 + im * 16 + mr;
                a[im] = *(const half8_*)(AsB + row * 128 + (((s * 4 + quad) ^ x7) * 16));
            }
#pragma unroll
            for (int in = 0; in < 4; in++) {
                int row = wn * 64 + in * 16 + mr;
                b[in] = *(const half8_*)(BsB + row * 128 + (((s * 4 + quad) ^ x7) * 16));
            }
#pragma unroll
            for (int im = 0; im < 4; im++)
#pragma unroll
                for (int in = 0; in < 4; in++)
                    acc[im][in] = __builtin_amdgcn_mfma_f32_16x16x32_f16(a[im], b[in], acc[im][in], 0, 0, 0);
        }
        __syncthreads();
    }

    float bv[4], gv[4], bev[4];
#pragma unroll
    for (int in = 0; in < 4; in++) {
        int colg = wn * 64 + in * 16 + mr;
        bv[in]  = bias[colg];
        gv[in]  = gamma[colg];
        bev[in] = beta[colg];
    }
    float* lnbuf   = (float*)AsB;
    float* lnstats = (float*)(AsB + 4096);

#pragma unroll
    for (int im = 0; im < 4; im++)
#pragma unroll
        for (int r = 0; r < 4; r++) {
            float s = 0.f, sq = 0.f;
#pragma unroll
            for (int in = 0; in < 4; in++) {
                float v = acc[im][in][r] + bv[in];
                v = v > 0.f ? v : 0.f;
                s += v; sq += v * v;
            }
            s  += __shfl_xor(s, 1, 64);  sq += __shfl_xor(sq, 1, 64);
            s  += __shfl_xor(s, 2, 64);  sq += __shfl_xor(sq, 2, 64);
            s  += __shfl_xor(s, 4, 64);  sq += __shfl_xor(sq, 4, 64);
            s  += __shfl_xor(s, 8, 64);  sq += __shfl_xor(sq, 8, 64);
            if (mr == 0) {
                int rl = wm * 64 + im * 16 + quad * 4 + r;
                lnbuf[(wn * 128 + rl) * 2]     = s;
                lnbuf[(wn * 128 + rl) * 2 + 1] = sq;
            }
        }
    __syncthreads();
    if (tid < 128) {
        float s  = lnbuf[tid * 2]             + lnbuf[(128 + tid) * 2]
                 + lnbuf[(256 + tid) * 2]     + lnbuf[(384 + tid) * 2];
        float sq = lnbuf[tid * 2 + 1]         + lnbuf[(128 + tid) * 2 + 1]
                 + lnbuf[(256 + tid) * 2 + 1] + lnbuf[(384 + tid) * 2 + 1];
        float mu  = s * (1.0f / 256.0f);
        float var = sq * (1.0f / 256.0f) - mu * mu;
        lnstats[tid * 2]     = mu;
        lnstats[tid * 2 + 1] = rsqrtf(var + EPS);
    }
    __syncthreads();

    _Float16* BsH = (_Float16*)BsB;
#pragma unroll
    for (int p = 0; p < 2; p++) {
        if (wm == p) {
#pragma unroll
            for (int im = 0; im < 4; im++)
#pragma unroll
                for (int r = 0; r < 4; r++) {
                    int rl = im * 16 + quad * 4 + r;
                    float mu = lnstats[(p * 64 + rl) * 2];
                    float rs = lnstats[(p * 64 + rl) * 2 + 1];
#pragma unroll
                    for (int in = 0; in < 4; in++) {
                        float v = acc[im][in][r] + bv[in];
                        v = v > 0.f ? v : 0.f;
                        BsH[rl * 256 + wn * 64 + in * 16 + mr] =
                            (_Float16)((v - mu) * rs * gv[in] + bev[in]);
                    }
                }
        }
        __syncthreads();
#pragma unroll
        for (int i = 0; i < 4; i++) {
            int c = i * 512 + tid;
            int row = c >> 5, ch = c & 31;
            half8_ v = *(const half8_*)(BsB + c * 16);
            *(half8_*)(H + (size_t)(rowBase + p * 64 + row) * 256 + ch * 8) = v;
        }
        __syncthreads();
    }

    // ===== appended output GEMM (acc dead; re-read own L2-warm H tile) =====
    if (Wfin != nullptr) {
        const int wm2 = w & 1;        // 64-row half
        const int wn2 = w >> 1;       // 32-col quarter (OUT=128)
        float4_ oacc[4][2];
#pragma unroll
        for (int ir = 0; ir < 4; ir++)
#pragma unroll
            for (int ic = 0; ic < 2; ic++) { float4_ z4 = {0.f, 0.f, 0.f, 0.f}; oacc[ir][ic] = z4; }
        // wave w stages rows [w*16, w*16+16) x 32 k-cols into As2[128][32] (linear)
        const _Float16* hG = H + (size_t)(rowBase + w * 16 + (lane >> 2)) * 256 + (lane & 3) * 8;
        void* lA = AsB + w * 1024;
#pragma unroll
        for (int k0 = 0; k0 < 256; k0 += 32) {
            gload16(hG + k0, lA);
            __syncthreads();
            half8_ a2[4], b2[2];
#pragma unroll
            for (int ir = 0; ir < 4; ir++)
                a2[ir] = *(const half8_*)(AsB + (wm2 * 64 + ir * 16 + mr) * 64 + quad * 16);
#pragma unroll
            for (int ic = 0; ic < 2; ic++)
                b2[ic] = *(const half8_*)(Wfin + (size_t)(wn2 * 32 + ic * 16 + mr) * 256 + k0 + quad * 8);
#pragma unroll
            for (int ir = 0; ir < 4; ir++)
#pragma unroll
                for (int ic = 0; ic < 2; ic++)
                    oacc[ir][ic] = __builtin_amdgcn_mfma_f32_16x16x32_f16(a2[ir], b2[ic], oacc[ir][ic], 0, 0, 0);
            __syncthreads();
        }
#pragma unroll
        for (int ic = 0; ic < 2; ic++) {
            int colg = wn2 * 32 + ic * 16 + mr;
            float bb = bfin[colg];
#pragma unroll
            for (int ir = 0; ir < 4; ir++) {
#pragma unroll
                for (int r = 0; r < 4; r++) {
                    int row = rowBase + wm2 * 64 + ir * 16 + quad * 4 + r;
                    if (row < N_NODES) outp[(size_t)row * 128 + colg] = oacc[ir][ic][r] + bb;
                }
            }
        }
    }
}

extern "C" void kernel_launch(void* const* d_in, const int* in_sizes, int n_in,
                              void* d_out, int out_size, void* d_ws, size_t ws_size,
                              hipStream_t stream) {
    const float* x    = (const float*)d_in[0];
    const int*   e1   = (const int*)d_in[1];
    const int*   e2   = (const int*)d_in[2];
    const float* Wl   = (const float*)d_in[3];
    const float* bl   = (const float*)d_in[4];
    const float* W0   = (const float*)d_in[5];
    const float* b0   = (const float*)d_in[6];
    const float* W1   = (const float*)d_in[7];
    const float* b1   = (const float*)d_in[8];
    const float* gamma= (const float*)d_in[9];
    const float* beta = (const float*)d_in[10];
    const float* Wout = (const float*)d_in[11];
    const float* bout = (const float*)d_in[12];

    char* ws = (char*)d_ws;
    size_t off = 0;
    auto alloc = [&](size_t bytes) -> char* {
        char* p = ws + off;
        off = (off + bytes + 255) & ~(size_t)255;
        return p;
    };
    _Float16* xh   = (_Float16*)alloc((size_t)NPAD * 256 * 2);
    _Float16* aggb = (_Float16*)alloc((size_t)NPAD * 256 * 2);
    _Float16* h1   = (_Float16*)alloc((size_t)NPAD * 256 * 2);
    _Float16* h2   = (_Float16*)alloc((size_t)NPAD * 256 * 2);
    _Float16* Wcat = (_Float16*)alloc((size_t)(2 * 256 * 768 + 128 * 256) * 2);
    float*    bias = (float*)alloc(640 * 4);
    unsigned long long* states = (unsigned long long*)alloc((size_t)2 * NSC2 * 8);
    int* G      = (int*)alloc((size_t)2 * NBLK * NBUCK * 4);
    int* start2 = (int*)alloc((size_t)2 * LFLAT * 4);
    int* rp     = (int*)alloc((size_t)2 * (N_NODES + 1) * 4);
    unsigned short* rank16 = (unsigned short*)alloc((size_t)2 * N_EDGES * 2);
    unsigned int*   tmp    = (unsigned int*)alloc((size_t)2 * N_EDGES * 4);
    int* col    = (int*)alloc((size_t)2 * N_EDGES * 4);

    int* rp1 = rp, *rp2 = rp + (N_NODES + 1);
    int* col1 = col, *col2 = col + N_EDGES;

    prep_kernel<<<14460, 256, 0, stream>>>(e1, e2, G, rank16, x, xh, aggb, h1,
                                           Wl, W0, W1, Wout, Wcat,
                                           bl, b0, b1, bout, bias, states);
    p2_scan<<<2 * NSC2, 256, 0, stream>>>(G, states, start2);
    p3_scatter<<<256, 256, 0, stream>>>(e1, e2, rank16, start2, tmp);
    p4_build<<<dim3(NBUCK, 2), 256, 0, stream>>>(tmp, start2, rp, col);

    const int nb4 = (N_NODES + 3) / 4;
    const _Float16* WoutH = Wcat + 393216;

    // layer 1: weights idx 1, edges r2, h_in = x
    gather_kernel<<<nb4, 256, 0, stream>>>(xh, rp2, col2, aggb, N_NODES);
    gemm_ln<<<391, 512, 0, stream>>>(aggb, xh, xh, Wcat + 196608,
                                     bias + 256, gamma + 256, beta + 256, h1,
                                     nullptr, nullptr, nullptr);
    // layer 2 + appended output GEMM (d_out = h2 @ Wout^T + bout)
    gather_kernel<<<nb4, 256, 0, stream>>>(h1, rp1, col1, aggb, N_NODES);
    gemm_ln<<<391, 512, 0, stream>>>(aggb, h1, xh, Wcat,
                                     bias, gamma, beta, h2,
                                     WoutH, bias + 512, (float*)d_out);
}